// Round 17
// baseline (258.373 us; speedup 1.0000x reference)
//
#include <hip/hip_runtime.h>
#include <hip/hip_bf16.h>

#define NB 4096
#define NT 50
#define NH 128
#define NINT 4
#define ROWS 64  // batch rows per block

typedef float f32x4 __attribute__((ext_vector_type(4)));
typedef __bf16 bf16x8 __attribute__((ext_vector_type(8)));
typedef short short8 __attribute__((ext_vector_type(8)));
typedef short short4s __attribute__((ext_vector_type(4)));

#define L2E 1.4426950408889634f

__device__ __forceinline__ float frcp(float x) { return __builtin_amdgcn_rcpf(x); }

// exp2(-x): v_exp_f32 computes 2^x; neg is a free src modifier.
__device__ __forceinline__ float exp2neg(float x) {
  float r;
  asm("v_exp_f32 %0, -%1" : "=v"(r) : "v"(x));
  return r;
}

__device__ __forceinline__ unsigned short bfbits(float f) {
  __bf16 b = (__bf16)f;  // native RTNE; pairs pack to v_cvt_pk_bf16_f32
  return __builtin_bit_cast(unsigned short, b);
}

// Grid: 256 blocks = NINT(4) * (NB/64).  Block: 512 threads = 8 waves, 1/CU.
// R17 = R15 (best passing, 188us) + ANTI-PHASE PAIR ORDER: the two waves
// sharing a SIMD process the two m-pairs in opposite order, so one wave's
// MFMA phase overlaps the other's VALU phase (R15 analysis: ~50% of step
// time is stall from the 2 waves/SIMD marching in phase lockstep; R16's
// in-wave pipeline attempt miscompiled -> parked).  Selector (w+(w>>2))&1
// anti-phases under both plausible wave->SIMD pairings (w%4 and w/2).
// Pure reordering: per-wave dataflow identical, all hm/acc indices stay
// compile-time (macro with literal pair ids).
// R9 LESSON: inline-asm v_mfma bypasses the MFMA hazard recognizer -> NaN.
// R3-R5 LESSON: weight-resident design needs the (512,2) 256-reg budget.
// R14 LESSON: count acc regs BEFORE adding accumulators; WRITE_SIZE is the
// spill tripwire.  R16 LESSON: cross-iteration-live acc arrays in hybrid
// unrolled pipelines miscompile silently — keep phase bodies self-contained.
__global__ __launch_bounds__(512, 2)
void gru_fused(const int* __restrict__ inputs, const float* __restrict__ emb,
               const float* __restrict__ w_int, const float* __restrict__ w_ih,
               const float* __restrict__ w_hh, const float* __restrict__ b_ih,
               const float* __restrict__ b_hh, const float* __restrict__ h0,
               float* __restrict__ out) {
  __shared__ unsigned short xs[2][ROWS * NH];  // 32 KB x tile, bf16, swizzled
  __shared__ unsigned short hs[2][ROWS * NH];  // 32 KB h tile, bf16, swizzled
  __shared__ int idxs[NT * ROWS];              // 12.8 KB token ids

  const int tid = threadIdx.x;
  const int bx = blockIdx.x;
  const int I = bx >> 6;          // interest 0..3
  const int R0 = (bx & 63) * ROWS;
  const int w = tid >> 6;         // wave 0..7
  const int lane = tid & 63;
  const int l15 = lane & 15;
  const int l4 = lane >> 4;
  const int oc0 = w * 16 + l4 * 4;  // lane's first h-col (owns oc0..oc0+3)
  const int po = (w + (w >> 2)) & 1;  // SIMD-pair anti-phase selector

  // staging/gather mapping: 8 threads per row, 16 floats (64B) each
  const int sr = tid >> 3;  // row 0..63
  const int sp = tid & 7;   // segment

  // ---- token indices ----
  for (int e = tid; e < NT * ROWS; e += 512) {
    int t = e >> 6, r = e & (ROWS - 1);
    idxs[e] = inputs[(size_t)(R0 + r) * NT + t];
  }
  __syncthreads();

  // ---- persistent weight fragments (96 VGPR, MFMA A-operands) + bias
  //      vectors, PRE-SCALED: gates r,i: *log2e; gate n: *2*log2e.
  //      A-frag: lane holds row(=oc_local)=lane&15, k=(lane>>4)*8 + 0..7
  bf16x8 wih[3][4], whh[3][4];
  f32x4 bR, bI, bNI, bNH;  // per-j bias vectors (j indexes oc0+j)
  {
    const float gs[3] = {L2E, L2E, 2.0f * L2E};
    #pragma unroll
    for (int g = 0; g < 3; ++g) {
      int oc = g * NH + w * 16 + l15;
      #pragma unroll
      for (int kk = 0; kk < 4; ++kk) {
        int k0 = kk * 32 + l4 * 8;
        const float* pi = w_ih + ((size_t)(I * 384 + oc) * NH + k0);
        const float* ph = w_hh + ((size_t)(I * 384 + oc) * NH + k0);
        bf16x8 si, sh;
        #pragma unroll
        for (int e = 0; e < 8; ++e) {
          si[e] = (__bf16)(pi[e] * gs[g]);
          sh[e] = (__bf16)(ph[e] * gs[g]);
        }
        wih[g][kk] = si;
        whh[g][kk] = sh;
      }
    }
    #pragma unroll
    for (int j = 0; j < 4; ++j) {
      bR[j] = (b_ih[I * 384 + oc0 + j] + b_hh[I * 384 + oc0 + j]) * L2E;
      bI[j] = (b_ih[I * 384 + NH + oc0 + j] + b_hh[I * 384 + NH + oc0 + j]) * L2E;
      bNI[j] = b_ih[I * 384 + 2 * NH + oc0 + j] * (2.0f * L2E);
      bNH[j] = b_hh[I * 384 + 2 * NH + oc0 + j] * (2.0f * L2E);
    }
  }

  // ---- w_interest A-frag (16 regs): interest i in row i (i<4), rows 4-15
  //      ZERO; scaled by 10*log2e so softmax is pure exp2 ----
  bf16x8 wg[4];
  #pragma unroll
  for (int kk = 0; kk < 4; ++kk) {
    bf16x8 f;
    #pragma unroll
    for (int e = 0; e < 8; ++e) {
      float v = (l15 < NINT)
                    ? w_int[l15 * NH + kk * 32 + l4 * 8 + e] * (10.0f * L2E)
                    : 0.0f;
      f[e] = (__bf16)v;
    }
    wg[kk] = f;
  }

  // ---- h0 master (fp32 regs) + initial bf16 LDS copy ----
  // Transposed D layout: row(batch) = m*16 + (lane&15), hcol = oc0 + j
  float hm[4][4];
  #pragma unroll
  for (int m = 0; m < 4; ++m) {
    int row = m * 16 + l15;
    short4s p;
    #pragma unroll
    for (int j = 0; j < 4; ++j) {
      float v = h0[((size_t)I * NB + R0 + row) * NH + oc0 + j];
      hm[m][j] = v;
      p[j] = (short)bfbits(v);
    }
    *(short4s*)&hs[0][(row * NH + oc0) ^ ((row & 7) << 3)] = p;
  }

  // ---- stage x(0) ----
  {
    const float4* src = (const float4*)(emb + (size_t)idxs[sr] * NH + sp * 16);
    float4 v0 = src[0], v1 = src[1], v2 = src[2], v3 = src[3];
    short8 s0, s1;
    s0[0] = bfbits(v0.x); s0[1] = bfbits(v0.y); s0[2] = bfbits(v0.z); s0[3] = bfbits(v0.w);
    s0[4] = bfbits(v1.x); s0[5] = bfbits(v1.y); s0[6] = bfbits(v1.z); s0[7] = bfbits(v1.w);
    s1[0] = bfbits(v2.x); s1[1] = bfbits(v2.y); s1[2] = bfbits(v2.z); s1[3] = bfbits(v2.w);
    s1[4] = bfbits(v3.x); s1[5] = bfbits(v3.y); s1[6] = bfbits(v3.z); s1[7] = bfbits(v3.w);
    int base = sr * NH + sp * 16;
    int sw = (sr & 7) << 3;
    *(short8*)&xs[0][base ^ sw] = s0;
    *(short8*)&xs[0][(base + 8) ^ sw] = s1;
  }
  __syncthreads();

// One m-pair: phase A (fragment reads + 56 MFMAs, 10 indep chains) then
// phase B (gate math + h-writeback).  MP is a LITERAL 0/1 so every
// hm/acc index is compile-time (rule #20 / R16 lesson).
#define GRU_PAIR(MP)                                                           \
  {                                                                            \
    f32x4 aG[2], aR[2], aI[2], aNI[2], aNH[2];                                 \
    __builtin_amdgcn_s_setprio(1);                                             \
    _Pragma("unroll")                                                          \
    for (int m2 = 0; m2 < 2; ++m2) {                                           \
      const int m = (MP)*2 + m2;                                               \
      aG[m2] = f32x4{0.0f, 0.0f, 0.0f, 0.0f};                                  \
      aR[m2] = bR; aI[m2] = bI; aNI[m2] = bNI; aNH[m2] = bNH;                  \
      int brow = m * 16 + l15;                                                 \
      int blin = brow * NH + l4 * 8;                                           \
      int sw2 = (brow & 7) << 3;                                               \
      _Pragma("unroll")                                                        \
      for (int kk = 0; kk < 4; ++kk) {                                         \
        int e = (blin + kk * 32) ^ sw2;                                        \
        bf16x8 bh = __builtin_bit_cast(bf16x8, *(const short8*)&hsc[e]);       \
        bf16x8 bx = __builtin_bit_cast(bf16x8, *(const short8*)&xsc[e]);       \
        aG[m2] = __builtin_amdgcn_mfma_f32_16x16x32_bf16(wg[kk], bx, aG[m2], 0, 0, 0);      \
        aR[m2] = __builtin_amdgcn_mfma_f32_16x16x32_bf16(wih[0][kk], bx, aR[m2], 0, 0, 0);  \
        aR[m2] = __builtin_amdgcn_mfma_f32_16x16x32_bf16(whh[0][kk], bh, aR[m2], 0, 0, 0);  \
        aI[m2] = __builtin_amdgcn_mfma_f32_16x16x32_bf16(wih[1][kk], bx, aI[m2], 0, 0, 0);  \
        aI[m2] = __builtin_amdgcn_mfma_f32_16x16x32_bf16(whh[1][kk], bh, aI[m2], 0, 0, 0);  \
        aNI[m2] = __builtin_amdgcn_mfma_f32_16x16x32_bf16(wih[2][kk], bx, aNI[m2], 0, 0, 0);\
        aNH[m2] = __builtin_amdgcn_mfma_f32_16x16x32_bf16(whh[2][kk], bh, aNH[m2], 0, 0, 0);\
      }                                                                        \
    }                                                                          \
    __builtin_amdgcn_s_setprio(0);                                             \
    _Pragma("unroll")                                                          \
    for (int m2 = 0; m2 < 2; ++m2) {                                           \
      const int m = (MP)*2 + m2;                                               \
      int brow = m * 16 + l15;                                                 \
      int sw2 = (brow & 7) << 3;                                               \
      float e0 = exp2neg(-aG[m2][0]), e1 = exp2neg(-aG[m2][1]);                \
      float e2 = exp2neg(-aG[m2][2]), e3 = exp2neg(-aG[m2][3]);                \
      float sel = (I == 0) ? e0 : (I == 1) ? e1 : (I == 2) ? e2 : e3;          \
      float gvl = sel * frcp(e0 + e1 + e2 + e3);                               \
      gvl = (gvl > 0.01f) ? gvl : 0.0f;                                        \
      const float gv = __shfl(gvl, l15, 64);                                   \
      short4s p;                                                               \
      _Pragma("unroll")                                                        \
      for (int j = 0; j < 4; ++j) {                                            \
        float rg = frcp(1.0f + exp2neg(aR[m2][j]));                            \
        float ig = frcp(1.0f + exp2neg(aI[m2][j]));                            \
        float an = fmaf(rg, aNH[m2][j], aNI[m2][j]);                           \
        float ng = fmaf(2.0f, frcp(1.0f + exp2neg(an)), -1.0f);                \
        float c = gv * ig;                                                     \
        float hy = fmaf(c, ng - hm[m][j], hm[m][j]);                           \
        hm[m][j] = hy;                                                         \
        p[j] = (short)bfbits(hy);                                              \
      }                                                                        \
      *(short4s*)&hsn[(brow * NH + oc0) ^ sw2] = p;                            \
    }                                                                          \
  }

  // ---- main recurrence ----
  for (int t = 0; t < NT; ++t) {
    const int cur = t & 1, nxt = cur ^ 1;
    const bool pf = (t + 1 < NT);

    // prefetch x(t+1) into regs; latency hides under the MFMA phases
    float4 v0, v1, v2, v3;
    if (pf) {
      const float4* src =
          (const float4*)(emb + (size_t)idxs[(t + 1) * ROWS + sr] * NH + sp * 16);
      v0 = src[0]; v1 = src[1]; v2 = src[2]; v3 = src[3];
    }

    const unsigned short* hsc = hs[cur];
    const unsigned short* xsc = xs[cur];
    unsigned short* hsn = hs[nxt];

    // anti-phase: SIMD-paired waves take the pairs in opposite order
    if (po == 0) {
      GRU_PAIR(0);
      GRU_PAIR(1);
    } else {
      GRU_PAIR(1);
      GRU_PAIR(0);
    }

    if (pf) {
      short8 s0, s1;
      s0[0] = bfbits(v0.x); s0[1] = bfbits(v0.y); s0[2] = bfbits(v0.z); s0[3] = bfbits(v0.w);
      s0[4] = bfbits(v1.x); s0[5] = bfbits(v1.y); s0[6] = bfbits(v1.z); s0[7] = bfbits(v1.w);
      s1[0] = bfbits(v2.x); s1[1] = bfbits(v2.y); s1[2] = bfbits(v2.z); s1[3] = bfbits(v2.w);
      s1[4] = bfbits(v3.x); s1[5] = bfbits(v3.y); s1[6] = bfbits(v3.z); s1[7] = bfbits(v3.w);
      int base = sr * NH + sp * 16;
      int sw = (sr & 7) << 3;
      *(short8*)&xs[nxt][base ^ sw] = s0;
      *(short8*)&xs[nxt][(base + 8) ^ sw] = s1;
    }
    __syncthreads();
  }

  // ---- epilogue: out[b][I][h], float4 per m ----
  #pragma unroll
  for (int m = 0; m < 4; ++m) {
    int row = m * 16 + l15;
    f32x4 o;
    #pragma unroll
    for (int j = 0; j < 4; ++j) o[j] = hm[m][j];
    *(f32x4*)&out[(size_t)(R0 + row) * (NINT * NH) + I * NH + oc0] = o;
  }
}

extern "C" void kernel_launch(void* const* d_in, const int* in_sizes, int n_in,
                              void* d_out, int out_size, void* d_ws, size_t ws_size,
                              hipStream_t stream) {
  const int* inputs = (const int*)d_in[0];
  const float* emb = (const float*)d_in[1];
  const float* w_int = (const float*)d_in[2];
  const float* w_ih = (const float*)d_in[3];
  const float* w_hh = (const float*)d_in[4];
  const float* b_ih = (const float*)d_in[5];
  const float* b_hh = (const float*)d_in[6];
  const float* h0 = (const float*)d_in[7];
  float* out = (float*)d_out;

  dim3 grid(NINT * (NB / ROWS));  // 256 blocks, one per CU
  dim3 block(512);
  gru_fused<<<grid, block, 0, stream>>>(inputs, emb, w_int, w_ih, w_hh, b_ih,
                                        b_hh, h0, out);
}

// Round 18
// 194.163 us; speedup vs baseline: 1.3307x; 1.3307x over previous
//
#include <hip/hip_runtime.h>
#include <hip/hip_bf16.h>

#define NB 4096
#define NT 50
#define NH 128
#define NINT 4
#define ROWS 64  // batch rows per block

typedef float f32x4 __attribute__((ext_vector_type(4)));
typedef __bf16 bf16x8 __attribute__((ext_vector_type(8)));
typedef short short8 __attribute__((ext_vector_type(8)));
typedef short short4s __attribute__((ext_vector_type(4)));

#define L2E 1.4426950408889634f

__device__ __forceinline__ float frcp(float x) { return __builtin_amdgcn_rcpf(x); }

// exp2(-x): v_exp_f32 computes 2^x; neg is a free src modifier.
__device__ __forceinline__ float exp2neg(float x) {
  float r;
  asm("v_exp_f32 %0, -%1" : "=v"(r) : "v"(x));
  return r;
}

__device__ __forceinline__ unsigned short bfbits(float f) {
  __bf16 b = (__bf16)f;  // native RTNE; pairs pack to v_cvt_pk_bf16_f32
  return __builtin_bit_cast(unsigned short, b);
}

// Grid: 256 blocks = NINT(4) * (NB/64).  Block: 512 threads = 8 waves, 1/CU.
// R18 = R13 structure + SPLIT ACCUMULATOR CHAINS.  Evidence: 161 GFLOP in
// 188us = 860 TF (34% peak); per SIMD-step MFMA issue is only ~1.1k cyc but
// MFMA-busy is ~3.4k -> each MFMA occupies ~15 cyc: DEPENDENCY-stalled.
// R7's gi+gh accumulator fusion (to save 2 adds) made the r,i chains 8-deep
// dependent MFMA chains; unfusing (aRx/aRh, aIx/aIh) makes ALL chains
// <=4-deep, 7 independent chains per m.  Live accs = 7 quads = 28 regs,
// STRICTLY BELOW R15's 40 (R14 spilled at 80) -> register-safe.
// R9 LESSON: inline-asm v_mfma bypasses the MFMA hazard recognizer -> NaN.
// R3-R5 LESSON: weight-resident design needs the (512,2) 256-reg budget.
// R14 LESSON: count acc regs BEFORE adding accumulators; WRITE_SIZE is the
// spill tripwire.  R16/R17 LESSON: phase/pipeline restructuring miscompiles
// or bloats; keep one m-body, emitted once.
__global__ __launch_bounds__(512, 2)
void gru_fused(const int* __restrict__ inputs, const float* __restrict__ emb,
               const float* __restrict__ w_int, const float* __restrict__ w_ih,
               const float* __restrict__ w_hh, const float* __restrict__ b_ih,
               const float* __restrict__ b_hh, const float* __restrict__ h0,
               float* __restrict__ out) {
  __shared__ unsigned short xs[2][ROWS * NH];  // 32 KB x tile, bf16, swizzled
  __shared__ unsigned short hs[2][ROWS * NH];  // 32 KB h tile, bf16, swizzled
  __shared__ int idxs[NT * ROWS];              // 12.8 KB token ids

  const int tid = threadIdx.x;
  const int bx = blockIdx.x;
  const int I = bx >> 6;          // interest 0..3
  const int R0 = (bx & 63) * ROWS;
  const int w = tid >> 6;         // wave 0..7
  const int lane = tid & 63;
  const int l15 = lane & 15;
  const int l4 = lane >> 4;
  const int oc0 = w * 16 + l4 * 4;  // lane's first h-col (owns oc0..oc0+3)

  // staging/gather mapping: 8 threads per row, 16 floats (64B) each
  const int sr = tid >> 3;  // row 0..63
  const int sp = tid & 7;   // segment

  // ---- token indices ----
  for (int e = tid; e < NT * ROWS; e += 512) {
    int t = e >> 6, r = e & (ROWS - 1);
    idxs[e] = inputs[(size_t)(R0 + r) * NT + t];
  }
  __syncthreads();

  // ---- persistent weight fragments (96 VGPR, MFMA A-operands) + bias
  //      vectors, PRE-SCALED: gates r,i: *log2e; gate n: *2*log2e.
  //      A-frag: lane holds row(=oc_local)=lane&15, k=(lane>>4)*8 + 0..7
  bf16x8 wih[3][4], whh[3][4];
  f32x4 bRI[2], bNI, bNH;  // x-side bias init (r,i carry BOTH biases)
  {
    const float gs[3] = {L2E, L2E, 2.0f * L2E};
    #pragma unroll
    for (int g = 0; g < 3; ++g) {
      int oc = g * NH + w * 16 + l15;
      #pragma unroll
      for (int kk = 0; kk < 4; ++kk) {
        int k0 = kk * 32 + l4 * 8;
        const float* pi = w_ih + ((size_t)(I * 384 + oc) * NH + k0);
        const float* ph = w_hh + ((size_t)(I * 384 + oc) * NH + k0);
        bf16x8 si, sh;
        #pragma unroll
        for (int e = 0; e < 8; ++e) {
          si[e] = (__bf16)(pi[e] * gs[g]);
          sh[e] = (__bf16)(ph[e] * gs[g]);
        }
        wih[g][kk] = si;
        whh[g][kk] = sh;
      }
    }
    #pragma unroll
    for (int j = 0; j < 4; ++j) {
      bRI[0][j] = (b_ih[I * 384 + oc0 + j] + b_hh[I * 384 + oc0 + j]) * L2E;
      bRI[1][j] = (b_ih[I * 384 + NH + oc0 + j] + b_hh[I * 384 + NH + oc0 + j]) * L2E;
      bNI[j] = b_ih[I * 384 + 2 * NH + oc0 + j] * (2.0f * L2E);
      bNH[j] = b_hh[I * 384 + 2 * NH + oc0 + j] * (2.0f * L2E);
    }
  }

  // ---- w_interest A-frag (16 regs): interest i in row i (i<4), rows 4-15
  //      ZERO; scaled by 10*log2e so softmax is pure exp2 ----
  bf16x8 wg[4];
  #pragma unroll
  for (int kk = 0; kk < 4; ++kk) {
    bf16x8 f;
    #pragma unroll
    for (int e = 0; e < 8; ++e) {
      float v = (l15 < NINT)
                    ? w_int[l15 * NH + kk * 32 + l4 * 8 + e] * (10.0f * L2E)
                    : 0.0f;
      f[e] = (__bf16)v;
    }
    wg[kk] = f;
  }

  // ---- h0 master (fp32 regs) + initial bf16 LDS copy ----
  // Transposed D layout: row(batch) = m*16 + (lane&15), hcol = oc0 + j
  float hm[4][4];
  #pragma unroll
  for (int m = 0; m < 4; ++m) {
    int row = m * 16 + l15;
    short4s p;
    #pragma unroll
    for (int j = 0; j < 4; ++j) {
      float v = h0[((size_t)I * NB + R0 + row) * NH + oc0 + j];
      hm[m][j] = v;
      p[j] = (short)bfbits(v);
    }
    *(short4s*)&hs[0][(row * NH + oc0) ^ ((row & 7) << 3)] = p;
  }

  // ---- stage x(0) ----
  {
    const float4* src = (const float4*)(emb + (size_t)idxs[sr] * NH + sp * 16);
    float4 v0 = src[0], v1 = src[1], v2 = src[2], v3 = src[3];
    short8 s0, s1;
    s0[0] = bfbits(v0.x); s0[1] = bfbits(v0.y); s0[2] = bfbits(v0.z); s0[3] = bfbits(v0.w);
    s0[4] = bfbits(v1.x); s0[5] = bfbits(v1.y); s0[6] = bfbits(v1.z); s0[7] = bfbits(v1.w);
    s1[0] = bfbits(v2.x); s1[1] = bfbits(v2.y); s1[2] = bfbits(v2.z); s1[3] = bfbits(v2.w);
    s1[4] = bfbits(v3.x); s1[5] = bfbits(v3.y); s1[6] = bfbits(v3.z); s1[7] = bfbits(v3.w);
    int base = sr * NH + sp * 16;
    int sw = (sr & 7) << 3;
    *(short8*)&xs[0][base ^ sw] = s0;
    *(short8*)&xs[0][(base + 8) ^ sw] = s1;
  }
  __syncthreads();

  // ---- main recurrence ----
  for (int t = 0; t < NT; ++t) {
    const int cur = t & 1, nxt = cur ^ 1;
    const bool pf = (t + 1 < NT);

    // prefetch x(t+1) into regs; latency hides under the MFMAs
    float4 v0, v1, v2, v3;
    if (pf) {
      const float4* src =
          (const float4*)(emb + (size_t)idxs[(t + 1) * ROWS + sr] * NH + sp * 16);
      v0 = src[0]; v1 = src[1]; v2 = src[2]; v3 = src[3];
    }

    const unsigned short* hsc = hs[cur];
    const unsigned short* xsc = xs[cur];
    unsigned short* hsn = hs[nxt];

    #pragma unroll
    for (int m = 0; m < 4; ++m) {
      // 7 SPLIT accumulators -> 7 independent chains, each <=4-deep
      f32x4 aG = f32x4{0.0f, 0.0f, 0.0f, 0.0f};
      f32x4 aRx = bRI[0], aRh = f32x4{0.0f, 0.0f, 0.0f, 0.0f};
      f32x4 aIx = bRI[1], aIh = f32x4{0.0f, 0.0f, 0.0f, 0.0f};
      f32x4 aNI = bNI, aNH = bNH;

      int brow = m * 16 + l15;        // B-frag col = batch row
      int blin = brow * NH + l4 * 8;  // bits 3-4
      int sw2 = (brow & 7) << 3;      // bits 3-5
      __builtin_amdgcn_s_setprio(1);
      #pragma unroll
      for (int kk = 0; kk < 4; ++kk) {
        int e = (blin + kk * 32) ^ sw2;  // kk*32: bits 5-6, carry-free; XOR full index
        bf16x8 bh = __builtin_bit_cast(bf16x8, *(const short8*)&hsc[e]);
        bf16x8 bx = __builtin_bit_cast(bf16x8, *(const short8*)&xsc[e]);
        // TRANSPOSED: A = weights, B = data -> D[oc][row]
        aG = __builtin_amdgcn_mfma_f32_16x16x32_bf16(wg[kk], bx, aG, 0, 0, 0);
        aRx = __builtin_amdgcn_mfma_f32_16x16x32_bf16(wih[0][kk], bx, aRx, 0, 0, 0);
        aRh = __builtin_amdgcn_mfma_f32_16x16x32_bf16(whh[0][kk], bh, aRh, 0, 0, 0);
        aIx = __builtin_amdgcn_mfma_f32_16x16x32_bf16(wih[1][kk], bx, aIx, 0, 0, 0);
        aIh = __builtin_amdgcn_mfma_f32_16x16x32_bf16(whh[1][kk], bh, aIh, 0, 0, 0);
        aNI = __builtin_amdgcn_mfma_f32_16x16x32_bf16(wih[2][kk], bx, aNI, 0, 0, 0);
        aNH = __builtin_amdgcn_mfma_f32_16x16x32_bf16(whh[2][kk], bh, aNH, 0, 0, 0);
      }
      __builtin_amdgcn_s_setprio(0);

      // gate softmax from aG (logits pre-scaled by 10*log2e, |s| small so no
      // max-subtraction); broadcast row gate from lane l15
      float e0 = exp2neg(-aG[0]), e1 = exp2neg(-aG[1]);
      float e2 = exp2neg(-aG[2]), e3 = exp2neg(-aG[3]);
      float sel = (I == 0) ? e0 : (I == 1) ? e1 : (I == 2) ? e2 : e3;
      float gvl = sel * frcp(e0 + e1 + e2 + e3);
      gvl = (gvl > 0.01f) ? gvl : 0.0f;
      const float gv = __shfl(gvl, l15, 64);

      short4s p;
      #pragma unroll
      for (int j = 0; j < 4; ++j) {
        float rg = frcp(1.0f + exp2neg(aRx[j] + aRh[j]));
        float ig = frcp(1.0f + exp2neg(aIx[j] + aIh[j]));
        float an = fmaf(rg, aNH[j], aNI[j]);
        float ng = fmaf(2.0f, frcp(1.0f + exp2neg(an)), -1.0f);
        float c = gv * ig;  // gv pre-thresholded
        float hy = fmaf(c, ng - hm[m][j], hm[m][j]);
        hm[m][j] = hy;
        p[j] = (short)bfbits(hy);
      }
      // packed h-writeback: 4 consecutive h-cols, one ds_write_b64
      *(short4s*)&hsn[(brow * NH + oc0) ^ sw2] = p;
    }

    if (pf) {
      short8 s0, s1;
      s0[0] = bfbits(v0.x); s0[1] = bfbits(v0.y); s0[2] = bfbits(v0.z); s0[3] = bfbits(v0.w);
      s0[4] = bfbits(v1.x); s0[5] = bfbits(v1.y); s0[6] = bfbits(v1.z); s0[7] = bfbits(v1.w);
      s1[0] = bfbits(v2.x); s1[1] = bfbits(v2.y); s1[2] = bfbits(v2.z); s1[3] = bfbits(v2.w);
      s1[4] = bfbits(v3.x); s1[5] = bfbits(v3.y); s1[6] = bfbits(v3.z); s1[7] = bfbits(v3.w);
      int base = sr * NH + sp * 16;
      int sw = (sr & 7) << 3;
      *(short8*)&xs[nxt][base ^ sw] = s0;
      *(short8*)&xs[nxt][(base + 8) ^ sw] = s1;
    }
    __syncthreads();
  }

  // ---- epilogue: out[b][I][h], float4 per m ----
  #pragma unroll
  for (int m = 0; m < 4; ++m) {
    int row = m * 16 + l15;
    f32x4 o;
    #pragma unroll
    for (int j = 0; j < 4; ++j) o[j] = hm[m][j];
    *(f32x4*)&out[(size_t)(R0 + row) * (NINT * NH) + I * NH + oc0] = o;
  }
}

extern "C" void kernel_launch(void* const* d_in, const int* in_sizes, int n_in,
                              void* d_out, int out_size, void* d_ws, size_t ws_size,
                              hipStream_t stream) {
  const int* inputs = (const int*)d_in[0];
  const float* emb = (const float*)d_in[1];
  const float* w_int = (const float*)d_in[2];
  const float* w_ih = (const float*)d_in[3];
  const float* w_hh = (const float*)d_in[4];
  const float* b_ih = (const float*)d_in[5];
  const float* b_hh = (const float*)d_in[6];
  const float* h0 = (const float*)d_in[7];
  float* out = (float*)d_out;

  dim3 grid(NINT * (NB / ROWS));  // 256 blocks, one per CU
  dim3 block(512);
  gru_fused<<<grid, block, 0, stream>>>(inputs, emb, w_int, w_ih, w_hh, b_ih,
                                        b_hh, h0, out);
}

// Round 20
// 182.712 us; speedup vs baseline: 1.4141x; 1.0627x over previous
//
#include <hip/hip_runtime.h>
#include <hip/hip_bf16.h>

#define NB 4096
#define NT 50
#define NH 128
#define NINT 4
#define ROWS 64  // batch rows per block

typedef float f32x4 __attribute__((ext_vector_type(4)));
typedef __bf16 bf16x8 __attribute__((ext_vector_type(8)));
typedef short short8 __attribute__((ext_vector_type(8)));
typedef short short4s __attribute__((ext_vector_type(4)));

#define L2E 1.4426950408889634f

__device__ __forceinline__ float frcp(float x) { return __builtin_amdgcn_rcpf(x); }

// 2^x via the BUILTIN (scheduler-visible).  R7-R18 used asm("v_exp_f32")
// which is opaque to the scheduler (can't model the ~16cy transcendental
// latency).  The builtin emits the same v_exp_f32; negation folds into a
// source modifier at the call sites.
__device__ __forceinline__ float exp2p(float x) { return __builtin_amdgcn_exp2f(x); }

__device__ __forceinline__ unsigned short bfbits(float f) {
  __bf16 b = (__bf16)f;  // native RTNE; pairs pack to v_cvt_pk_bf16_f32
  return __builtin_bit_cast(unsigned short, b);
}

// Grid: 256 blocks = NINT(4) * (NB/64).  Block: 512 threads = 8 waves, 1/CU.
// R20 = R15 VERBATIM (best fully-passing, 188us) + exp2 builtin swap ONLY.
// R19 added wg-replication + shfl-removal and diverged on post-timing
// revalidation (first check passed, replay state differed) — that dataflow
// is REVERTED wholesale; exp2p is numerically/structurally inert.
// Lever scorecard: algebraic VALU cuts worked (R7 -42us); LDS-volume null
// (R12/R13); chain-depth null (R18); occupancy/crew/pipeline/anti-phase
// infeasible or regressed (R3-5,R11,R14,R16,R17); gate-shfl-removal
// diverged (R19).
// R9 LESSON: inline-asm v_mfma bypasses the MFMA hazard recognizer -> NaN.
// R3-R5 LESSON: weight-resident design needs the (512,2) 256-reg budget.
// R14 LESSON: count acc regs BEFORE adding (pairs = 40 live, measured safe);
// WRITE_SIZE is the spill tripwire.
__global__ __launch_bounds__(512, 2)
void gru_fused(const int* __restrict__ inputs, const float* __restrict__ emb,
               const float* __restrict__ w_int, const float* __restrict__ w_ih,
               const float* __restrict__ w_hh, const float* __restrict__ b_ih,
               const float* __restrict__ b_hh, const float* __restrict__ h0,
               float* __restrict__ out) {
  __shared__ unsigned short xs[2][ROWS * NH];  // 32 KB x tile, bf16, swizzled
  __shared__ unsigned short hs[2][ROWS * NH];  // 32 KB h tile, bf16, swizzled
  __shared__ int idxs[NT * ROWS];              // 12.8 KB token ids

  const int tid = threadIdx.x;
  const int bx = blockIdx.x;
  const int I = bx >> 6;          // interest 0..3
  const int R0 = (bx & 63) * ROWS;
  const int w = tid >> 6;         // wave 0..7
  const int lane = tid & 63;
  const int l15 = lane & 15;
  const int l4 = lane >> 4;
  const int oc0 = w * 16 + l4 * 4;  // lane's first h-col (owns oc0..oc0+3)

  // staging/gather mapping: 8 threads per row, 16 floats (64B) each
  const int sr = tid >> 3;  // row 0..63
  const int sp = tid & 7;   // segment

  // ---- token indices ----
  for (int e = tid; e < NT * ROWS; e += 512) {
    int t = e >> 6, r = e & (ROWS - 1);
    idxs[e] = inputs[(size_t)(R0 + r) * NT + t];
  }
  __syncthreads();

  // ---- persistent weight fragments (96 VGPR, MFMA A-operands) + bias
  //      vectors, PRE-SCALED: gates r,i: *log2e; gate n: *2*log2e.
  //      A-frag: lane holds row(=oc_local)=lane&15, k=(lane>>4)*8 + 0..7
  bf16x8 wih[3][4], whh[3][4];
  f32x4 bR, bI, bNI, bNH;  // per-j bias vectors (j indexes oc0+j)
  {
    const float gs[3] = {L2E, L2E, 2.0f * L2E};
    #pragma unroll
    for (int g = 0; g < 3; ++g) {
      int oc = g * NH + w * 16 + l15;
      #pragma unroll
      for (int kk = 0; kk < 4; ++kk) {
        int k0 = kk * 32 + l4 * 8;
        const float* pi = w_ih + ((size_t)(I * 384 + oc) * NH + k0);
        const float* ph = w_hh + ((size_t)(I * 384 + oc) * NH + k0);
        bf16x8 si, sh;
        #pragma unroll
        for (int e = 0; e < 8; ++e) {
          si[e] = (__bf16)(pi[e] * gs[g]);
          sh[e] = (__bf16)(ph[e] * gs[g]);
        }
        wih[g][kk] = si;
        whh[g][kk] = sh;
      }
    }
    #pragma unroll
    for (int j = 0; j < 4; ++j) {
      bR[j] = (b_ih[I * 384 + oc0 + j] + b_hh[I * 384 + oc0 + j]) * L2E;
      bI[j] = (b_ih[I * 384 + NH + oc0 + j] + b_hh[I * 384 + NH + oc0 + j]) * L2E;
      bNI[j] = b_ih[I * 384 + 2 * NH + oc0 + j] * (2.0f * L2E);
      bNH[j] = b_hh[I * 384 + 2 * NH + oc0 + j] * (2.0f * L2E);
    }
  }

  // ---- w_interest A-frag (16 regs): interest i in row i (i<4), rows 4-15
  //      ZERO; scaled by 10*log2e so softmax is pure exp2 (R15 form) ----
  bf16x8 wg[4];
  #pragma unroll
  for (int kk = 0; kk < 4; ++kk) {
    bf16x8 f;
    #pragma unroll
    for (int e = 0; e < 8; ++e) {
      float v = (l15 < NINT)
                    ? w_int[l15 * NH + kk * 32 + l4 * 8 + e] * (10.0f * L2E)
                    : 0.0f;
      f[e] = (__bf16)v;
    }
    wg[kk] = f;
  }

  // ---- h0 master (fp32 regs) + initial bf16 LDS copy ----
  // Transposed D layout: row(batch) = m*16 + (lane&15), hcol = oc0 + j
  float hm[4][4];
  #pragma unroll
  for (int m = 0; m < 4; ++m) {
    int row = m * 16 + l15;
    short4s p;
    #pragma unroll
    for (int j = 0; j < 4; ++j) {
      float v = h0[((size_t)I * NB + R0 + row) * NH + oc0 + j];
      hm[m][j] = v;
      p[j] = (short)bfbits(v);
    }
    *(short4s*)&hs[0][(row * NH + oc0) ^ ((row & 7) << 3)] = p;
  }

  // ---- stage x(0) ----
  {
    const float4* src = (const float4*)(emb + (size_t)idxs[sr] * NH + sp * 16);
    float4 v0 = src[0], v1 = src[1], v2 = src[2], v3 = src[3];
    short8 s0, s1;
    s0[0] = bfbits(v0.x); s0[1] = bfbits(v0.y); s0[2] = bfbits(v0.z); s0[3] = bfbits(v0.w);
    s0[4] = bfbits(v1.x); s0[5] = bfbits(v1.y); s0[6] = bfbits(v1.z); s0[7] = bfbits(v1.w);
    s1[0] = bfbits(v2.x); s1[1] = bfbits(v2.y); s1[2] = bfbits(v2.z); s1[3] = bfbits(v2.w);
    s1[4] = bfbits(v3.x); s1[5] = bfbits(v3.y); s1[6] = bfbits(v3.z); s1[7] = bfbits(v3.w);
    int base = sr * NH + sp * 16;
    int sw = (sr & 7) << 3;
    *(short8*)&xs[0][base ^ sw] = s0;
    *(short8*)&xs[0][(base + 8) ^ sw] = s1;
  }
  __syncthreads();

  // ---- main recurrence ----
  for (int t = 0; t < NT; ++t) {
    const int cur = t & 1, nxt = cur ^ 1;
    const bool pf = (t + 1 < NT);

    // prefetch x(t+1) into regs; latency hides under the MFMA phases
    float4 v0, v1, v2, v3;
    if (pf) {
      const float4* src =
          (const float4*)(emb + (size_t)idxs[(t + 1) * ROWS + sr] * NH + sp * 16);
      v0 = src[0]; v1 = src[1]; v2 = src[2]; v3 = src[3];
    }

    const unsigned short* hsc = hs[cur];
    const unsigned short* xsc = xs[cur];
    unsigned short* hsn = hs[nxt];

    #pragma unroll
    for (int mp = 0; mp < 2; ++mp) {
      // pair-local accumulators: 10 quads = 40 regs (measured safe in R15)
      f32x4 aG[2], aR[2], aI[2], aNI[2], aNH[2];

      // ---- PHASE A: both m's fragment reads + 56 MFMAs (10 indep chains) --
      __builtin_amdgcn_s_setprio(1);
      #pragma unroll
      for (int m2 = 0; m2 < 2; ++m2) {
        const int m = mp * 2 + m2;
        aG[m2] = f32x4{0.0f, 0.0f, 0.0f, 0.0f};
        aR[m2] = bR; aI[m2] = bI; aNI[m2] = bNI; aNH[m2] = bNH;
        int brow = m * 16 + l15;        // B-frag col = batch row
        int blin = brow * NH + l4 * 8;  // bits 3-4
        int sw2 = (brow & 7) << 3;      // bits 3-5
        #pragma unroll
        for (int kk = 0; kk < 4; ++kk) {
          int e = (blin + kk * 32) ^ sw2;  // carry-free add; XOR full index
          bf16x8 bh = __builtin_bit_cast(bf16x8, *(const short8*)&hsc[e]);
          bf16x8 bx = __builtin_bit_cast(bf16x8, *(const short8*)&xsc[e]);
          // TRANSPOSED: A = weights, B = data -> D[oc][row]
          aG[m2] = __builtin_amdgcn_mfma_f32_16x16x32_bf16(wg[kk], bx, aG[m2], 0, 0, 0);
          aR[m2] = __builtin_amdgcn_mfma_f32_16x16x32_bf16(wih[0][kk], bx, aR[m2], 0, 0, 0);
          aR[m2] = __builtin_amdgcn_mfma_f32_16x16x32_bf16(whh[0][kk], bh, aR[m2], 0, 0, 0);
          aI[m2] = __builtin_amdgcn_mfma_f32_16x16x32_bf16(wih[1][kk], bx, aI[m2], 0, 0, 0);
          aI[m2] = __builtin_amdgcn_mfma_f32_16x16x32_bf16(whh[1][kk], bh, aI[m2], 0, 0, 0);
          aNI[m2] = __builtin_amdgcn_mfma_f32_16x16x32_bf16(wih[2][kk], bx, aNI[m2], 0, 0, 0);
          aNH[m2] = __builtin_amdgcn_mfma_f32_16x16x32_bf16(whh[2][kk], bh, aNH[m2], 0, 0, 0);
        }
      }
      __builtin_amdgcn_s_setprio(0);

      // ---- PHASE B: both m's gate math + h-writeback ----------------------
      #pragma unroll
      for (int m2 = 0; m2 < 2; ++m2) {
        const int m = mp * 2 + m2;
        int brow = m * 16 + l15;
        int sw2 = (brow & 7) << 3;

        // gate softmax from aG (logits pre-scaled by 10*log2e, |s| small so
        // no max-subtraction); broadcast row gate from lane l15 (R15 form)
        float e0 = exp2p(aG[m2][0]), e1 = exp2p(aG[m2][1]);
        float e2 = exp2p(aG[m2][2]), e3 = exp2p(aG[m2][3]);
        float sel = (I == 0) ? e0 : (I == 1) ? e1 : (I == 2) ? e2 : e3;
        float gvl = sel * frcp(e0 + e1 + e2 + e3);
        gvl = (gvl > 0.01f) ? gvl : 0.0f;
        const float gv = __shfl(gvl, l15, 64);

        short4s p;
        #pragma unroll
        for (int j = 0; j < 4; ++j) {
          float rg = frcp(1.0f + exp2p(-aR[m2][j]));
          float ig = frcp(1.0f + exp2p(-aI[m2][j]));
          float an = fmaf(rg, aNH[m2][j], aNI[m2][j]);
          float ng = fmaf(2.0f, frcp(1.0f + exp2p(-an)), -1.0f);
          float c = gv * ig;  // gv pre-thresholded
          float hy = fmaf(c, ng - hm[m][j], hm[m][j]);
          hm[m][j] = hy;
          p[j] = (short)bfbits(hy);
        }
        // packed h-writeback: 4 consecutive h-cols, one ds_write_b64
        *(short4s*)&hsn[(brow * NH + oc0) ^ sw2] = p;
      }
    }

    if (pf) {
      short8 s0, s1;
      s0[0] = bfbits(v0.x); s0[1] = bfbits(v0.y); s0[2] = bfbits(v0.z); s0[3] = bfbits(v0.w);
      s0[4] = bfbits(v1.x); s0[5] = bfbits(v1.y); s0[6] = bfbits(v1.z); s0[7] = bfbits(v1.w);
      s1[0] = bfbits(v2.x); s1[1] = bfbits(v2.y); s1[2] = bfbits(v2.z); s1[3] = bfbits(v2.w);
      s1[4] = bfbits(v3.x); s1[5] = bfbits(v3.y); s1[6] = bfbits(v3.z); s1[7] = bfbits(v3.w);
      int base = sr * NH + sp * 16;
      int sw = (sr & 7) << 3;
      *(short8*)&xs[nxt][base ^ sw] = s0;
      *(short8*)&xs[nxt][(base + 8) ^ sw] = s1;
    }
    __syncthreads();
  }

  // ---- epilogue: out[b][I][h], float4 per m ----
  #pragma unroll
  for (int m = 0; m < 4; ++m) {
    int row = m * 16 + l15;
    f32x4 o;
    #pragma unroll
    for (int j = 0; j < 4; ++j) o[j] = hm[m][j];
    *(f32x4*)&out[(size_t)(R0 + row) * (NINT * NH) + I * NH + oc0] = o;
  }
}

extern "C" void kernel_launch(void* const* d_in, const int* in_sizes, int n_in,
                              void* d_out, int out_size, void* d_ws, size_t ws_size,
                              hipStream_t stream) {
  const int* inputs = (const int*)d_in[0];
  const float* emb = (const float*)d_in[1];
  const float* w_int = (const float*)d_in[2];
  const float* w_ih = (const float*)d_in[3];
  const float* w_hh = (const float*)d_in[4];
  const float* b_ih = (const float*)d_in[5];
  const float* b_hh = (const float*)d_in[6];
  const float* h0 = (const float*)d_in[7];
  float* out = (float*)d_out;

  dim3 grid(NINT * (NB / ROWS));  // 256 blocks, one per CU
  dim3 block(512);
  gru_fused<<<grid, block, 0, stream>>>(inputs, emb, w_int, w_ih, w_hh, b_ih,
                                        b_hh, h0, out);
}